// Round 2
// baseline (130.354 us; speedup 1.0000x reference)
//
#include <hip/hip_runtime.h>
#include <stdint.h>

// Problem: out[m,e,k] = sum_n A[m,n] * W[e,n,k]
// == GEMM C[8192,2048] = A[8192,1024] x B[1024,2048], B[n, e*32+k] = W[e,n,k]
//
// Round-6 structure: m201-style 4-phase-per-K-tile schedule with counted vmcnt.
// 256x256 tile, 8 waves (2x4), BK=64, 16 K-tiles, double-buffered LDS (128 KB).
// Per K-tile, phases (h, ihalf): [ds_read frags; stage ONE 16KB half of tile
// t+1 (2 x global_load_lds); counted vmcnt at ph2 (4) / ph4 (2) ONLY; barrier;
// lgkmcnt(0)+sched_barrier; setprio(1); 16 MFMA; setprio(0); barrier].
// Staging order per tile t: A-rows0(t+1), A-rows1(t+1), B-kh0(t+1), B-kh1(t+1),
// always into the other buffer. vmcnt(4)@ph2 guarantees B-kh1(t) before ph3;
// vmcnt(2)@ph4 guarantees A0/A1/B0(t+1) before next tile. Never vmcnt(0) in
// the steady loop (T3+T4); tile 15 peeled with vmcnt(0)@ph2. T5 setprio kept.
// A LDS: [256 rows][8 grp][8] XOR-swizzled (grp ^ row&7), proven conflict-free.
// B LDS: [8 kg][256 col][8] natural, conflict-free (octet-distinct slots).
// Grid 256 = 1 block/CU; XCD swizzle: XCD x owns j-slice x (B-slice L2-resident).

#define M_DIM 8192
#define N_IN  1024   // reduction dim
#define E_DIM 64
#define K_DIM 32
#define J_DIM 2048   // E*K output columns

typedef __attribute__((ext_vector_type(8))) __bf16 bf16x8;
typedef __attribute__((ext_vector_type(4))) float floatx4;
typedef __attribute__((address_space(3))) unsigned short lds_u16;

__device__ inline unsigned short f2bf(float f) {
    union { float f; unsigned u; } v; v.f = f;
    unsigned u = v.u;
    u += 0x7fff + ((u >> 16) & 1);   // round-to-nearest-even
    return (unsigned short)(u >> 16);
}

// A [8192,1024] f32 -> Ab bf16 (same row-major layout). 4 elements/thread.
__global__ __launch_bounds__(256) void convert_A(const float* __restrict__ A,
                                                 unsigned short* __restrict__ Ab) {
    size_t i = (size_t)blockIdx.x * 256 + threadIdx.x;
    const float4 v = ((const float4*)A)[i];
    ushort4 o;
    o.x = f2bf(v.x); o.y = f2bf(v.y); o.z = f2bf(v.z); o.w = f2bf(v.w);
    ((ushort4*)Ab)[i] = o;
}

// W [64][1024][32] f32 -> BG[kgroup=n>>3][j=e*32+k][t=n&7] bf16  (128 x 2048 x 8).
__global__ __launch_bounds__(256) void convert_W(const float* __restrict__ W,
                                                 unsigned short* __restrict__ BG) {
    const int t   = threadIdx.x;
    const int e   = blockIdx.y;        // 0..63
    const int n0  = blockIdx.x * 64;   // 16 slabs
    const int k   = t & 31;
    const int oct = t >> 5;            // 8 octets of n within the slab
    const float* Wp = W + ((size_t)e * N_IN + n0 + oct * 8) * K_DIM + k;
    unsigned short tmp[8];
#pragma unroll
    for (int u = 0; u < 8; ++u) tmp[u] = f2bf(Wp[(size_t)u * K_DIM]);  // coalesced per u
    unsigned short* out = BG + ((size_t)((n0 >> 3) + oct) * J_DIM + e * K_DIM + k) * 8;
    ushort4 lo, hi;
    lo.x = tmp[0]; lo.y = tmp[1]; lo.z = tmp[2]; lo.w = tmp[3];
    hi.x = tmp[4]; hi.y = tmp[5]; hi.z = tmp[6]; hi.w = tmp[7];
    ((ushort4*)out)[0] = lo;
    ((ushort4*)out)[1] = hi;
}

#define GLDS(SRC, DST)                                                          \
    __builtin_amdgcn_global_load_lds(                                           \
        (const __attribute__((address_space(1))) unsigned int*)(SRC),           \
        (__attribute__((address_space(3))) unsigned int*)(DST), 16, 0, 0)

// Stage A row-half HALF (128 rows x 64 k) of K-tile T1 into LDS buffer NA.
#define STAGE_A(NA, T1, HALF)                                                   \
    { _Pragma("unroll")                                                         \
      for (int c = 0; c < 2; ++c)                                               \
          GLDS(gA0 + (size_t)((HALF) * 128 + c * 64) * N_IN + (size_t)(T1) * 64,\
               (NA) + (HALF) * 8192 + c * 4096 + wave * 512); }

// Stage B k-half KH (4 kgroups x 256 cols) of K-tile T1 into LDS buffer NB.
#define STAGE_B(NB, T1, KH)                                                     \
    { _Pragma("unroll")                                                         \
      for (int c = 0; c < 2; ++c)                                               \
          GLDS(gB0 + ((size_t)(T1) * 8 + (KH) * 4 + c * 2) * (J_DIM * 8),       \
               (NB) + (KH) * 8192 + c * 4096 + dstB0); }

#define WAIT_VM(N) asm volatile("s_waitcnt vmcnt(" #N ")" ::: "memory")

// One phase: frag ds_reads, stage, (counted wait), barrier, lgkm drain,
// prio-wrapped 16-MFMA cluster, barrier. sched_barrier(0) pins each boundary.
#define PHASE(CA, CB, H, IH, READB, STAGE_STMT, WAIT_STMT)                      \
    {                                                                           \
        if (READB) {                                                            \
            _Pragma("unroll")                                                   \
            for (int j = 0; j < 4; ++j)                                         \
                bfr[j] = *(const __attribute__((address_space(3))) bf16x8*)     \
                         ((CB) + (H) * 8192 + bbase + j * 128);                 \
        }                                                                       \
        bf16x8 af[4];                                                           \
        _Pragma("unroll")                                                       \
        for (int ii = 0; ii < 4; ++ii)                                          \
            af[ii] = *(const __attribute__((address_space(3))) bf16x8*)         \
                     ((CA) + arow + ((IH) * 4 + ii) * 1024 + (sA0 ^ ((H) << 5)));\
        STAGE_STMT;                                                             \
        WAIT_STMT;                                                              \
        __builtin_amdgcn_s_barrier();                                           \
        asm volatile("s_waitcnt lgkmcnt(0)" ::: "memory");                      \
        __builtin_amdgcn_sched_barrier(0);                                      \
        __builtin_amdgcn_s_setprio(1);                                          \
        _Pragma("unroll")                                                       \
        for (int ii = 0; ii < 4; ++ii) {                                        \
            _Pragma("unroll")                                                   \
            for (int j = 0; j < 4; ++j)                                         \
                acc[(IH) * 4 + ii][j] = __builtin_amdgcn_mfma_f32_16x16x32_bf16(\
                    af[ii], bfr[j], acc[(IH) * 4 + ii][j], 0, 0, 0);            \
        }                                                                       \
        __builtin_amdgcn_s_setprio(0);                                          \
        __builtin_amdgcn_s_barrier();                                           \
        __builtin_amdgcn_sched_barrier(0);                                      \
    }

__global__ __launch_bounds__(512, 2) void gemm_bt(const unsigned short* __restrict__ Ab,
                                                  const unsigned short* __restrict__ BG,
                                                  float* __restrict__ C) {
    __shared__ unsigned short As0[16384];   // A tile buf0: [256 rows][8 grp][8]
    __shared__ unsigned short As1[16384];
    __shared__ unsigned short Bs0[16384];   // B tile buf0: [8 kg][256 col][8]
    __shared__ unsigned short Bs1[16384];

    const int tid  = threadIdx.x;
    const int wave = tid >> 6;       // 0..7
    const int lane = tid & 63;
    const int wm = wave >> 2;        // 0..1  (M-half of 256)
    const int wn = wave & 3;         // 0..3  (N-quarter of 256)

    const int orig = blockIdx.x;     // 256 blocks = 8 j x 32 m, XCD = orig%8
    const int m0 = (orig >> 3) * 256;
    const int j0 = (orig & 7) * 256;

    const int l7 = lane & 7, l15 = lane & 15, quad = lane >> 4, lrow8 = lane >> 3;

    // Staging bases. A: lane l covers LDS slot (row=l>>3, grp=l&7), fetching
    // pre-swizzled global group (l&7)^(l>>3). B: fully contiguous chunks.
    const unsigned short* gA0 = Ab + (size_t)(m0 + wave * 8 + lrow8) * N_IN
                                   + ((l7 ^ lrow8) << 3);
    const unsigned short* gB0 = BG + ((size_t)(tid >> 8) * J_DIM + j0 + (tid & 255)) * 8;
    const int dstB0 = (tid >> 8) * 2048 + ((tid >> 6) & 3) * 512;

    lds_u16* const A0p = (lds_u16*)As0;
    lds_u16* const A1p = (lds_u16*)As1;
    lds_u16* const B0p = (lds_u16*)Bs0;
    lds_u16* const B1p = (lds_u16*)Bs1;

    floatx4 acc[8][4];
#pragma unroll
    for (int i = 0; i < 8; ++i)
#pragma unroll
        for (int j = 0; j < 4; ++j) acc[i][j] = (floatx4)(0.0f);

    // Fragment-read addressing
    const int arow  = (wm * 128 + l15) * 64;          // A row base (shorts)
    const int sA0   = (quad ^ l7) << 3;               // A group slot, h flips bit2 (<<5 bytes.. shorts)
    const int bbase = (quad * 256 + wn * 64 + l15) * 8;

    // --- prologue: stage all 4 halves of tile 0 into buffer 0 ---------------
    STAGE_A(A0p, 0, 0);
    STAGE_A(A0p, 0, 1);
    STAGE_B(B0p, 0, 0);
    STAGE_B(B0p, 0, 1);
    WAIT_VM(2);                       // A0,A1,B0 done; B1(0) may be in flight
    __builtin_amdgcn_s_barrier();
    __builtin_amdgcn_sched_barrier(0);

    lds_u16* cA = A0p; lds_u16* cB = B0p;
    lds_u16* nA = A1p; lds_u16* nB = B1p;
    bf16x8 bfr[4];

    for (int t = 0; t < 15; ++t) {
        PHASE(cA, cB, 0, 0, 1, STAGE_A(nA, t + 1, 0), (void)0);
        PHASE(cA, cB, 0, 1, 0, STAGE_A(nA, t + 1, 1), WAIT_VM(4)); // B-kh1(t) ready for ph3
        PHASE(cA, cB, 1, 0, 1, STAGE_B(nB, t + 1, 0), (void)0);
        PHASE(cA, cB, 1, 1, 0, STAGE_B(nB, t + 1, 1), WAIT_VM(2)); // A0/A1/B0(t+1) ready
        lds_u16* sw;
        sw = cA; cA = nA; nA = sw;
        sw = cB; cB = nB; nB = sw;
    }
    // --- tile 15 (peeled): no staging; drain B-kh1(15) before ph3 -----------
    PHASE(cA, cB, 0, 0, 1, (void)0, (void)0);
    PHASE(cA, cB, 0, 1, 0, (void)0, WAIT_VM(0));
    PHASE(cA, cB, 1, 0, 1, (void)0, (void)0);
    PHASE(cA, cB, 1, 1, 0, (void)0, (void)0);

    // Epilogue: C/D layout col = lane&15, row = (lane>>4)*4 + reg
    const int crow = quad * 4;
#pragma unroll
    for (int i = 0; i < 8; ++i) {
#pragma unroll
        for (int j = 0; j < 4; ++j) {
            float* Cp = C + (size_t)(m0 + wm * 128 + i * 16 + crow) * J_DIM
                          + (j0 + wn * 64 + j * 16 + l15);
#pragma unroll
            for (int r = 0; r < 4; ++r)
                Cp[(size_t)r * J_DIM] = acc[i][j][r];
        }
    }
}

extern "C" void kernel_launch(void* const* d_in, const int* in_sizes, int n_in,
                              void* d_out, int out_size, void* d_ws, size_t ws_size,
                              hipStream_t stream) {
    const float* A = (const float*)d_in[0];   // [8192,1024]
    const float* W = (const float*)d_in[1];   // [64,1024,32]
    float* out = (float*)d_out;               // [8192,64,32] == [8192,2048]

    unsigned short* Ab = (unsigned short*)d_ws;                 // 16 MB
    unsigned short* BG = Ab + (size_t)M_DIM * N_IN;             // +4 MB

    convert_A<<<M_DIM * N_IN / (256 * 4), 256, 0, stream>>>(A, Ab);
    convert_W<<<dim3(N_IN / 64, E_DIM), 256, 0, stream>>>(W, BG);
    gemm_bt<<<dim3(256), dim3(512), 0, stream>>>(Ab, BG, out);
}

// Round 5
// 126.447 us; speedup vs baseline: 1.0309x; 1.0309x over previous
//
#include <hip/hip_runtime.h>
#include <stdint.h>

// Problem: out[m,e,k] = sum_n A[m,n] * W[e,n,k]
// == GEMM C[8192,2048] = A[8192,1024] x B[1024,2048], B[n, e*32+k] = W[e,n,k]
//
// Round-9 = Round-7 pipeline, bug-fixed (RD_B reads cB, not cA) and
// race-hardened (LGKM(0) before the c3 barrier: no wave may cross the barrier
// with ds_reads of the retiring buffer in flight while others DMA-write it).
//
// Structure: register-ping-pong software pipeline, ONE barrier per K-tile.
// 256x256 tile, 8 waves (2x4), BK=64, 16 K-tiles, double-buffered LDS (128 KB).
// Per K-tile, 4 clusters of 16 MFMA: each cluster ISSUES the next cluster's
// ds_reads, then counted s_waitcnt lgkmcnt(N) (DS completes in-order) +
// sched_barrier(0), then MFMAs on fragments already in registers. The LDS pipe
// fills WHILE the MFMA pipe drains (overlap, not sum).
// Steady state: 12 DS ops outstanding at each wait; LGKM(4/8) drains exactly
// the fragments the next MFMA cluster consumes (trace in session journal).
// Buffer recycling: vmcnt(0)+lgkmcnt(0)+s_barrier at cluster 3 per tile, the
// vmcnt issued ~3 MFMA clusters after the staging DMAs -> near-free drain.
// Staging of t+1: A (HBM/L3) at c0, B (L2) at c1.
// A LDS: [256 rows][8 grp][8] XOR-swizzled (grp ^ row&7), conflict-free.
// B LDS: [8 kg][256 col][8] natural, conflict-free.
// Grid 256 = 1 block/CU; XCD swizzle: XCD x owns j-slice x (B slice L2-resident).

#define M_DIM 8192
#define N_IN  1024   // reduction dim
#define E_DIM 64
#define K_DIM 32
#define J_DIM 2048   // E*K output columns

typedef __attribute__((ext_vector_type(8))) __bf16 bf16x8;
typedef __attribute__((ext_vector_type(4))) float floatx4;
typedef __attribute__((address_space(3))) unsigned short lds_u16;

__device__ inline unsigned short f2bf(float f) {
    union { float f; unsigned u; } v; v.f = f;
    unsigned u = v.u;
    u += 0x7fff + ((u >> 16) & 1);   // round-to-nearest-even
    return (unsigned short)(u >> 16);
}

// A [8192,1024] f32 -> Ab bf16 (same row-major layout). 4 elements/thread.
__global__ __launch_bounds__(256) void convert_A(const float* __restrict__ A,
                                                 unsigned short* __restrict__ Ab) {
    size_t i = (size_t)blockIdx.x * 256 + threadIdx.x;
    const float4 v = ((const float4*)A)[i];
    ushort4 o;
    o.x = f2bf(v.x); o.y = f2bf(v.y); o.z = f2bf(v.z); o.w = f2bf(v.w);
    ((ushort4*)Ab)[i] = o;
}

// W [64][1024][32] f32 -> BG[kgroup=n>>3][j=e*32+k][t=n&7] bf16  (128 x 2048 x 8).
__global__ __launch_bounds__(256) void convert_W(const float* __restrict__ W,
                                                 unsigned short* __restrict__ BG) {
    const int t   = threadIdx.x;
    const int e   = blockIdx.y;        // 0..63
    const int n0  = blockIdx.x * 64;   // 16 slabs
    const int k   = t & 31;
    const int oct = t >> 5;            // 8 octets of n within the slab
    const float* Wp = W + ((size_t)e * N_IN + n0 + oct * 8) * K_DIM + k;
    unsigned short tmp[8];
#pragma unroll
    for (int u = 0; u < 8; ++u) tmp[u] = f2bf(Wp[(size_t)u * K_DIM]);  // coalesced per u
    unsigned short* out = BG + ((size_t)((n0 >> 3) + oct) * J_DIM + e * K_DIM + k) * 8;
    ushort4 lo, hi;
    lo.x = tmp[0]; lo.y = tmp[1]; lo.z = tmp[2]; lo.w = tmp[3];
    hi.x = tmp[4]; hi.y = tmp[5]; hi.z = tmp[6]; hi.w = tmp[7];
    ((ushort4*)out)[0] = lo;
    ((ushort4*)out)[1] = hi;
}

#define GLDS(SRC, DST)                                                          \
    __builtin_amdgcn_global_load_lds(                                           \
        (const __attribute__((address_space(1))) unsigned int*)(SRC),           \
        (__attribute__((address_space(3))) unsigned int*)(DST), 16, 0, 0)

// Stage A row-half HALF (128 rows x 64 k) of K-tile T1 into LDS buffer NA.
#define STAGE_A(NA, T1, HALF)                                                   \
    { _Pragma("unroll")                                                         \
      for (int c = 0; c < 2; ++c)                                               \
          GLDS(gA0 + (size_t)((HALF) * 128 + c * 64) * N_IN + (size_t)(T1) * 64,\
               (NA) + (HALF) * 8192 + c * 4096 + wave * 512); }

// Stage B k-half KH (4 kgroups x 256 cols) of K-tile T1 into LDS buffer NB.
#define STAGE_B(NB, T1, KH)                                                     \
    { _Pragma("unroll")                                                         \
      for (int c = 0; c < 2; ++c)                                               \
          GLDS(gB0 + ((size_t)(T1) * 8 + (KH) * 4 + c * 2) * (J_DIM * 8),       \
               (NB) + (KH) * 8192 + c * 4096 + dstB0); }

#define WAIT_VM(N) asm volatile("s_waitcnt vmcnt(" #N ")" ::: "memory")
#define LGKM(N)    asm volatile("s_waitcnt lgkmcnt(" #N ")" ::: "memory")
#define SB()       __builtin_amdgcn_sched_barrier(0)

// Fragment loads (explicit LDS address space -> ds_read_b128).
#define RD_A(DST, CA, H, IH)                                                    \
    { _Pragma("unroll")                                                         \
      for (int ii = 0; ii < 4; ++ii)                                            \
          DST[ii] = *(const __attribute__((address_space(3))) bf16x8*)          \
                    ((CA) + arow + ((IH) * 4 + ii) * 1024 + (sA0 ^ ((H) << 5))); }

#define RD_B(DST, CB, H)                                                        \
    { _Pragma("unroll")                                                         \
      for (int j = 0; j < 4; ++j)                                               \
          DST[j] = *(const __attribute__((address_space(3))) bf16x8*)           \
                   ((CB) + (H) * 8192 + bbase + j * 128); }

// 16-MFMA cluster on register-resident fragments (T5 setprio wrap).
#define MFMA_CL(AF, BF, IH)                                                     \
    { __builtin_amdgcn_s_setprio(1);                                            \
      _Pragma("unroll")                                                         \
      for (int ii = 0; ii < 4; ++ii) {                                          \
          _Pragma("unroll")                                                     \
          for (int j = 0; j < 4; ++j)                                           \
              acc[(IH) * 4 + ii][j] = __builtin_amdgcn_mfma_f32_16x16x32_bf16(  \
                  AF[ii], BF[j], acc[(IH) * 4 + ii][j], 0, 0, 0);               \
      }                                                                         \
      __builtin_amdgcn_s_setprio(0); }

__global__ __launch_bounds__(512, 2) void gemm_bt(const unsigned short* __restrict__ Ab,
                                                  const unsigned short* __restrict__ BG,
                                                  float* __restrict__ C) {
    __shared__ unsigned short As0[16384];   // A tile buf0: [256 rows][8 grp][8]
    __shared__ unsigned short As1[16384];
    __shared__ unsigned short Bs0[16384];   // B tile buf0: [8 kg][256 col][8]
    __shared__ unsigned short Bs1[16384];

    const int tid  = threadIdx.x;
    const int wave = tid >> 6;       // 0..7
    const int lane = tid & 63;
    const int wm = wave >> 2;        // 0..1  (M-half of 256)
    const int wn = wave & 3;         // 0..3  (N-quarter of 256)

    const int orig = blockIdx.x;     // 256 blocks = 8 j x 32 m, XCD = orig%8
    const int m0 = (orig >> 3) * 256;
    const int j0 = (orig & 7) * 256;

    const int l7 = lane & 7, l15 = lane & 15, quad = lane >> 4, lrow8 = lane >> 3;

    // Staging bases. A: lane l covers LDS slot (row=l>>3, grp=l&7), fetching
    // pre-swizzled global group (l&7)^(l>>3). B: fully contiguous chunks.
    const unsigned short* gA0 = Ab + (size_t)(m0 + wave * 8 + lrow8) * N_IN
                                   + ((l7 ^ lrow8) << 3);
    const unsigned short* gB0 = BG + ((size_t)(tid >> 8) * J_DIM + j0 + (tid & 255)) * 8;
    const int dstB0 = (tid >> 8) * 2048 + ((tid >> 6) & 3) * 512;

    lds_u16* cA = (lds_u16*)As0;
    lds_u16* cB = (lds_u16*)Bs0;
    lds_u16* nA = (lds_u16*)As1;
    lds_u16* nB = (lds_u16*)Bs1;

    floatx4 acc[8][4];
#pragma unroll
    for (int i = 0; i < 8; ++i)
#pragma unroll
        for (int j = 0; j < 4; ++j) acc[i][j] = (floatx4)(0.0f);

    // Fragment-read addressing
    const int arow  = (wm * 128 + l15) * 64;          // A row base (shorts)
    const int sA0   = (quad ^ l7) << 3;               // A slot-group (shorts); h flips bit 2
    const int bbase = (quad * 256 + wn * 64 + l15) * 8;

    // --- prologue: stage tile 0, then pre-read cluster-0 fragments ----------
    STAGE_A(cA, 0, 0);
    STAGE_A(cA, 0, 1);
    STAGE_B(cB, 0, 0);
    STAGE_B(cB, 0, 1);
    WAIT_VM(0);
    __builtin_amdgcn_s_barrier();
    SB();

    bf16x8 afA[4], afB[4], bfA[4], bfB[4];
    RD_A(afA, cA, 0, 0);
    RD_B(bfA, cB, 0);

    // --- main loop: 15 tiles with staging, clusters c0..c3 ------------------
    for (int t = 0; t < 15; ++t) {
        // c0: MFMA(h0,i0-3) | issue A(h0,i4-7) reads + stage A(t+1)
        RD_A(afB, cA, 0, 1);
        STAGE_A(nA, t + 1, 0);
        STAGE_A(nA, t + 1, 1);
        LGKM(4); SB();                  // drains prior tile's c3 reads (afA,bfA)
        MFMA_CL(afA, bfA, 0);

        // c1: MFMA(h0,i4-7) | issue A(h1,i0-3)+B(h1) reads + stage B(t+1)
        RD_A(afA, cA, 1, 0);
        RD_B(bfB, cB, 1);
        STAGE_B(nB, t + 1, 0);
        STAGE_B(nB, t + 1, 1);
        LGKM(8); SB();                  // drains c0's 4 (afB ready)
        MFMA_CL(afB, bfA, 1);

        // c2: MFMA(h1,i0-3) | issue A(h1,i4-7) reads
        RD_A(afB, cA, 1, 1);
        LGKM(4); SB();                  // drains c1's 8 (afA,bfB ready)
        MFMA_CL(afA, bfB, 0);

        // c3: recycle barrier, then issue cluster-0 reads of tile t+1
        WAIT_VM(0);                     // own staging DMAs of t+1 done
        LGKM(0);                        // own ds_reads of retiring bufs done
        __builtin_amdgcn_s_barrier();   // => ALL waves: staged t+1, no reads
                                        //    of retiring buffers in flight
        SB();
        { lds_u16* sw = cA; cA = nA; nA = sw; }
        { lds_u16* sw = cB; cB = nB; nB = sw; }
        RD_A(afA, cA, 0, 0);
        RD_B(bfA, cB, 0);
        LGKM(8); SB();                  // no-op wait; afB/bfB already resident
        MFMA_CL(afB, bfB, 1);
    }

    // --- tail tile 15 (no staging) ------------------------------------------
    RD_A(afB, cA, 0, 1);
    LGKM(4); SB();                      // drains c3's 8 (afA,bfA ready)
    MFMA_CL(afA, bfA, 0);
    RD_A(afA, cA, 1, 0);
    RD_B(bfB, cB, 1);
    LGKM(8); SB();                      // drains tail-c0's 4 (afB ready)
    MFMA_CL(afB, bfA, 1);
    RD_A(afB, cA, 1, 1);
    LGKM(4); SB();                      // drains tail-c1's 8 (afA,bfB ready)
    MFMA_CL(afA, bfB, 0);
    LGKM(0); SB();                      // drains tail-c2's 4 (afB ready)
    MFMA_CL(afB, bfB, 1);

    // Epilogue: C/D layout col = lane&15, row = (lane>>4)*4 + reg
    const int crow = quad * 4;
#pragma unroll
    for (int i = 0; i < 8; ++i) {
#pragma unroll
        for (int j = 0; j < 4; ++j) {
            float* Cp = C + (size_t)(m0 + wm * 128 + i * 16 + crow) * J_DIM
                          + (j0 + wn * 64 + j * 16 + l15);
#pragma unroll
            for (int r = 0; r < 4; ++r)
                Cp[(size_t)r * J_DIM] = acc[i][j][r];
        }
    }
}

extern "C" void kernel_launch(void* const* d_in, const int* in_sizes, int n_in,
                              void* d_out, int out_size, void* d_ws, size_t ws_size,
                              hipStream_t stream) {
    const float* A = (const float*)d_in[0];   // [8192,1024]
    const float* W = (const float*)d_in[1];   // [64,1024,32]
    float* out = (float*)d_out;               // [8192,64,32] == [8192,2048]

    unsigned short* Ab = (unsigned short*)d_ws;                 // 16 MB
    unsigned short* BG = Ab + (size_t)M_DIM * N_IN;             // +4 MB

    convert_A<<<M_DIM * N_IN / (256 * 4), 256, 0, stream>>>(A, Ab);
    convert_W<<<dim3(N_IN / 64, E_DIM), 256, 0, stream>>>(W, BG);
    gemm_bt<<<dim3(256), dim3(512), 0, stream>>>(Ab, BG, out);
}